// Round 15
// baseline (520.802 us; speedup 1.0000x reference)
//
#include <hip/hip_runtime.h>

typedef __attribute__((ext_vector_type(4))) float f32x4;
typedef __attribute__((ext_vector_type(8))) short s16x8;
typedef __attribute__((ext_vector_type(4))) unsigned short u16x4;

__device__ __forceinline__ unsigned short f2bf(float f) {
    union { float f; unsigned int u; } v; v.f = f;
    unsigned int r = v.u + 0x7fffu + ((v.u >> 16) & 1u);
    return (unsigned short)(r >> 16);
}
// byte offset into a [48][256] bf16 LDS tile, XOR-swizzled (row stride 512B)
__device__ __forceinline__ unsigned int swz(int row, int col) {
    return (unsigned int)(row * 512 + col * 2) ^ (((unsigned int)row & 7u) << 4);
}
// byte offset into a [28][256] f32 LDS tile, XOR-swizzled (row stride 1024B)
__device__ __forceinline__ unsigned int swz32(int row, int col) {
    return (unsigned int)(row * 1024 + col * 4) ^ (((unsigned int)row & 7u) << 4);
}

// Weights pre-packed in MFMA B-fragment order:
// wt2[m][ct][kt][lane][e] = bf16(W_m[kt*32 + (lane>>4)*8 + e][ct*16 + (lane&15)])
__global__ void prep_w(const float* __restrict__ wq, const float* __restrict__ wk,
                       const float* __restrict__ wv, const float* __restrict__ wo,
                       unsigned short* __restrict__ wt2) {
    int idx = blockIdx.x * 256 + threadIdx.x;   // 0..32767
    int lane = idx & 63;
    int kt   = (idx >> 6) & 7;
    int nt   = (idx >> 9) & 15;
    int m    = idx >> 13;
    const float* W = (m == 0) ? wq : (m == 1) ? wk : (m == 2) ? wv : wo;
    int g = lane & 15, uu = lane >> 4;
    int n = nt * 16 + g;
    unsigned short* dst = wt2 + (size_t)idx * 8;
    #pragma unroll
    for (int e = 0; e < 8; ++e) {
        int k = kt * 32 + uu * 8 + e;
        dst[e] = f2bf(W[k * 256 + n]);
    }
}

__global__ __launch_bounds__(256, 2)
void fused_attn(const float* __restrict__ br0, const float* __restrict__ br1,
                const float* __restrict__ br2, const unsigned short* __restrict__ wt2,
                const float* __restrict__ bq, const float* __restrict__ bk,
                const float* __restrict__ bv, const float* __restrict__ bo,
                float* __restrict__ out) {
    // 64 KB static LDS forces <=2 blocks/CU (the proven weight-L2-residency regime).
    // Xs: [0, 24576) bf16 X / later O. Ys: [32768, 61440) f32 staged output (no alias).
    __shared__ char ldsb[65536];
    char* Xs = ldsb;
    char* Ys = ldsb + 32768;

    const int t    = threadIdx.x;
    const int wave = t >> 6;            // = head index
    const int lane = t & 63;
    const int g    = lane & 15;
    const int u    = lane >> 4;
    const int b     = blockIdx.x >> 6;  // 512 blocks: 64 chunks per batch
    const int chunk = blockIdx.x & 63;  // 64-position chunk, 4 tiles of 16
    const int nb   = wave * 64;         // head column base
    const int cc   = lane * 4;

    const s16x8* WF = (const s16x8*)wt2;   // fragment-ordered weights

    #pragma unroll 1
    for (int il = 0; il < 4; ++il) {
        const int l0 = (chunk << 6) + (il << 4);

        // ---------------- phase 1: stage X (fused up-interp), bf16 swizzled ------------
        {
            #pragma unroll
            for (int it = 0; it < 12; ++it) {
                int r = it * 4 + wave;      // wave-uniform row
                int n = r >> 4, p = r & 15;
                int l = l0 + p;
                float4 v;
                if (n == 0) {
                    v = *(const float4*)(br0 + (size_t)(b * 4096 + l) * 256 + cc);
                } else {
                    const float* src = (n == 1) ? br1 : br2;
                    int   Lin   = (n == 1) ? 2048 : 1024;
                    float scale = (n == 1) ? 0.5f : 0.25f;
                    float sp = (l + 0.5f) * scale - 0.5f;
                    sp = fminf(fmaxf(sp, 0.0f), (float)(Lin - 1));
                    int i0 = (int)sp;
                    int i1 = min(i0 + 1, Lin - 1);
                    float w = sp - (float)i0;
                    float4 a0 = *(const float4*)(src + (size_t)(b * Lin + i0) * 256 + cc);
                    float4 a1 = *(const float4*)(src + (size_t)(b * Lin + i1) * 256 + cc);
                    v.x = a0.x * (1.0f - w) + a1.x * w;
                    v.y = a0.y * (1.0f - w) + a1.y * w;
                    v.z = a0.z * (1.0f - w) + a1.z * w;
                    v.w = a0.w * (1.0f - w) + a1.w * w;
                }
                u16x4 h;
                h.x = f2bf(v.x); h.y = f2bf(v.y); h.z = f2bf(v.z); h.w = f2bf(v.w);
                *(u16x4*)(Xs + swz(r, cc)) = h;
            }
        }
        __syncthreads();                                    // B1

        // ------- phase 2: Q+K projection, KT-OUTER (8 weight loads in flight per kt) ---
        float sc[3][3][4];                     // scores -> attention weights (in place)
        {
            f32x4 qc[4][3], kc[4][3];
            #pragma unroll
            for (int tc = 0; tc < 4; ++tc)
                #pragma unroll
                for (int n = 0; n < 3; ++n) {
                    qc[tc][n] = (f32x4){0.f, 0.f, 0.f, 0.f};
                    kc[tc][n] = (f32x4){0.f, 0.f, 0.f, 0.f};
                }

            __builtin_amdgcn_s_setprio(1);
            #pragma unroll
            for (int kt = 0; kt < 8; ++kt) {
                s16x8 a[3];
                #pragma unroll
                for (int n = 0; n < 3; ++n)
                    a[n] = *(const s16x8*)(Xs + swz(n * 16 + g, kt * 32 + u * 8));
                s16x8 bfq[4], bfk[4];
                #pragma unroll
                for (int tc = 0; tc < 4; ++tc) {
                    const int ct = wave * 4 + tc;
                    bfq[tc] = WF[((0 * 16 + ct) * 8 + kt) * 64 + lane];
                    bfk[tc] = WF[((1 * 16 + ct) * 8 + kt) * 64 + lane];
                }
                #pragma unroll
                for (int tc = 0; tc < 4; ++tc)
                    #pragma unroll
                    for (int n = 0; n < 3; ++n) {
                        qc[tc][n] = __builtin_amdgcn_mfma_f32_16x16x32_bf16(a[n], bfq[tc], qc[tc][n], 0, 0, 0);
                        kc[tc][n] = __builtin_amdgcn_mfma_f32_16x16x32_bf16(a[n], bfk[tc], kc[tc][n], 0, 0, 0);
                    }
            }
            __builtin_amdgcn_s_setprio(0);

            // scores: dot over the head's 64 dims = sum over tc (bias added per tc)
            #pragma unroll
            for (int n = 0; n < 3; ++n)
                #pragma unroll
                for (int m = 0; m < 3; ++m)
                    #pragma unroll
                    for (int j = 0; j < 4; ++j) sc[n][m][j] = 0.f;
            #pragma unroll
            for (int tc = 0; tc < 4; ++tc) {
                const float Bqv = bq[nb + tc * 16 + g];
                const float Bkv = bk[nb + tc * 16 + g];
                #pragma unroll
                for (int n = 0; n < 3; ++n)
                    #pragma unroll
                    for (int j = 0; j < 4; ++j) {
                        qc[tc][n][j] += Bqv;
                        kc[tc][n][j] += Bkv;
                    }
                #pragma unroll
                for (int n = 0; n < 3; ++n)
                    #pragma unroll
                    for (int m = 0; m < 3; ++m)
                        #pragma unroll
                        for (int j = 0; j < 4; ++j)
                            sc[n][m][j] += qc[tc][n][j] * kc[tc][m][j];
            }
            // reduce over the 16 lanes (g) of each row group
            #pragma unroll
            for (int mask = 1; mask < 16; mask <<= 1)
                #pragma unroll
                for (int n = 0; n < 3; ++n)
                    #pragma unroll
                    for (int m = 0; m < 3; ++m)
                        #pragma unroll
                        for (int j = 0; j < 4; ++j)
                            sc[n][m][j] += __shfl_xor(sc[n][m][j], mask, 16);
            // softmax over m (scale 1/sqrt(64)), in place
            #pragma unroll
            for (int n = 0; n < 3; ++n)
                #pragma unroll
                for (int j = 0; j < 4; ++j) {
                    float s0 = sc[n][0][j] * 0.125f;
                    float s1 = sc[n][1][j] * 0.125f;
                    float s2 = sc[n][2][j] * 0.125f;
                    float mx = fmaxf(s0, fmaxf(s1, s2));
                    float e0 = __expf(s0 - mx), e1 = __expf(s1 - mx), e2 = __expf(s2 - mx);
                    float inv = 1.0f / (e0 + e1 + e2);
                    sc[n][0][j] = e0 * inv;
                    sc[n][1][j] = e1 * inv;
                    sc[n][2][j] = e2 * inv;
                }
        }

        // ------------- phase 3: V projection (kt-outer, 4 loads in flight) -------------
        f32x4 vacc[3][4];
        #pragma unroll
        for (int n = 0; n < 3; ++n)
            #pragma unroll
            for (int tc = 0; tc < 4; ++tc)
                vacc[n][tc] = (f32x4){0.f, 0.f, 0.f, 0.f};
        __builtin_amdgcn_s_setprio(1);
        #pragma unroll
        for (int kt = 0; kt < 8; ++kt) {
            s16x8 a[3];
            #pragma unroll
            for (int n = 0; n < 3; ++n)
                a[n] = *(const s16x8*)(Xs + swz(n * 16 + g, kt * 32 + u * 8));
            s16x8 bfv[4];
            #pragma unroll
            for (int tc = 0; tc < 4; ++tc)
                bfv[tc] = WF[((2 * 16 + wave * 4 + tc) * 8 + kt) * 64 + lane];
            #pragma unroll
            for (int tc = 0; tc < 4; ++tc)
                #pragma unroll
                for (int n = 0; n < 3; ++n)
                    vacc[n][tc] = __builtin_amdgcn_mfma_f32_16x16x32_bf16(a[n], bfv[tc], vacc[n][tc], 0, 0, 0);
        }
        __builtin_amdgcn_s_setprio(0);
        #pragma unroll
        for (int tc = 0; tc < 4; ++tc) {
            const float Bvv = bv[nb + tc * 16 + g];
            #pragma unroll
            for (int n = 0; n < 3; ++n)
                #pragma unroll
                for (int j = 0; j < 4; ++j)
                    vacc[n][tc][j] += Bvv;
        }
        __syncthreads();    // B2: all X reads complete before overwriting Xs with O

        // ------------- phase 4: O = attn @ V (per-lane), write bf16 to Xs --------------
        #pragma unroll
        for (int n = 0; n < 3; ++n)
            #pragma unroll
            for (int tc = 0; tc < 4; ++tc)
                #pragma unroll
                for (int j = 0; j < 4; ++j) {
                    float o = sc[n][0][j] * vacc[0][tc][j] +
                              sc[n][1][j] * vacc[1][tc][j] +
                              sc[n][2][j] * vacc[2][tc][j];
                    *(unsigned short*)(Xs + swz(n * 16 + u * 4 + j, nb + tc * 16 + g)) = f2bf(o);
                }
        __syncthreads();    // B3: O complete before cross-head reads

        // ------------- phase 5: output projection (kt-outer, 4 loads in flight) --------
        f32x4 yacc[3][4];
        #pragma unroll
        for (int n = 0; n < 3; ++n)
            #pragma unroll
            for (int tc = 0; tc < 4; ++tc)
                yacc[n][tc] = (f32x4){0.f, 0.f, 0.f, 0.f};
        __builtin_amdgcn_s_setprio(1);
        #pragma unroll
        for (int kt = 0; kt < 8; ++kt) {
            s16x8 a[3];
            #pragma unroll
            for (int n = 0; n < 3; ++n)
                a[n] = *(const s16x8*)(Xs + swz(n * 16 + g, kt * 32 + u * 8));
            s16x8 bfo[4];
            #pragma unroll
            for (int tc = 0; tc < 4; ++tc)
                bfo[tc] = WF[((3 * 16 + wave * 4 + tc) * 8 + kt) * 64 + lane];
            #pragma unroll
            for (int tc = 0; tc < 4; ++tc)
                #pragma unroll
                for (int n = 0; n < 3; ++n)
                    yacc[n][tc] = __builtin_amdgcn_mfma_f32_16x16x32_bf16(a[n], bfo[tc], yacc[n][tc], 0, 0, 0);
        }
        __builtin_amdgcn_s_setprio(0);

        // ------------- phase 6: stage Y (bias + down-interp) into LDS f32 (no alias) ---
        #pragma unroll
        for (int tc = 0; tc < 4; ++tc) {
            int col = nb + tc * 16 + g;
            const float Bov = bo[col];
            #pragma unroll
            for (int j = 0; j < 4; ++j)
                *(float*)(Ys + swz32(u * 4 + j, col)) = yacc[0][tc][j] + Bov;
            #pragma unroll
            for (int jj = 0; jj < 2; ++jj)
                *(float*)(Ys + swz32(16 + u * 2 + jj, col)) =
                    0.5f * (yacc[1][tc][2 * jj] + yacc[1][tc][2 * jj + 1]) + Bov;
            *(float*)(Ys + swz32(24 + u, col)) =
                0.5f * (yacc[2][tc][1] + yacc[2][tc][2]) + Bov;
        }
        __syncthreads();    // B4: Ys ready (also orders next-tile Xs writes after phase-5 reads)

        // ------------- phase 7: coalesced f32x4 stores ---------------------------------
        {
            // branch0: 16 rows
            #pragma unroll
            for (int it = 0; it < 4; ++it) {
                int r = it * 4 + wave;
                f32x4 v = *(const f32x4*)(Ys + swz32(r, cc));
                *(f32x4*)(out + (size_t)(b * 4096 + l0 + r) * 256 + cc) = v;
            }
            // branch1: 8 rows
            #pragma unroll
            for (int it = 0; it < 2; ++it) {
                int q = it * 4 + wave;
                f32x4 v = *(const f32x4*)(Ys + swz32(16 + q, cc));
                *(f32x4*)(out + 8388608 + (size_t)(b * 2048 + (l0 >> 1) + q) * 256 + cc) = v;
            }
            // branch2: 4 rows
            {
                f32x4 v = *(const f32x4*)(Ys + swz32(24 + wave, cc));
                *(f32x4*)(out + 12582912 + (size_t)(b * 1024 + (l0 >> 2) + wave) * 256 + cc) = v;
            }
        }
        // next iteration's B1 orders phase-1 Xs writes after this tile's reads;
        // barrier collectiveness means no wave can reach phase 6 (Ys writes) of tile
        // il+1 before all waves finished these Ys reads (they must cross B1/B2/B3 first).
    }
}

extern "C" void kernel_launch(void* const* d_in, const int* in_sizes, int n_in,
                              void* d_out, int out_size, void* d_ws, size_t ws_size,
                              hipStream_t stream) {
    const float* br0 = (const float*)d_in[0];
    const float* br1 = (const float*)d_in[1];
    const float* br2 = (const float*)d_in[2];
    const float* Wq  = (const float*)d_in[3];
    const float* bq  = (const float*)d_in[4];
    const float* Wk  = (const float*)d_in[5];
    const float* bk  = (const float*)d_in[6];
    const float* Wv  = (const float*)d_in[7];
    const float* bv  = (const float*)d_in[8];
    const float* Wo  = (const float*)d_in[9];
    const float* bo  = (const float*)d_in[10];

    unsigned short* wt2 = (unsigned short*)d_ws;  // 4*256*256 bf16 = 512 KB, fragment order

    prep_w<<<128, 256, 0, stream>>>(Wq, Wk, Wv, Wo, wt2);
    fused_attn<<<512, 256, 0, stream>>>(br0, br1, br2, wt2, bq, bk, bv, bo,
                                        (float*)d_out);
}

// Round 16
// 117.521 us; speedup vs baseline: 4.4316x; 4.4316x over previous
//
#include <hip/hip_runtime.h>

typedef __attribute__((ext_vector_type(4))) float f32x4;
typedef __attribute__((ext_vector_type(8))) short s16x8;
typedef __attribute__((ext_vector_type(4))) unsigned short u16x4;

__device__ __forceinline__ unsigned short f2bf(float f) {
    union { float f; unsigned int u; } v; v.f = f;
    unsigned int r = v.u + 0x7fffu + ((v.u >> 16) & 1u);
    return (unsigned short)(r >> 16);
}
__device__ __forceinline__ float bf2f(unsigned short h) {
    union { unsigned int u; float f; } v; v.u = ((unsigned int)h) << 16;
    return v.f;
}
// byte offset into a [rows][256] bf16 LDS tile, XOR-swizzled (row stride 512B)
__device__ __forceinline__ unsigned int swz(int row, int col) {
    return (unsigned int)(row * 512 + col * 2) ^ (((unsigned int)row & 7u) << 4);
}

// Weights pre-packed in MFMA B-fragment order:
// wt2[m][ct][kt][lane][e] = bf16(W_m[kt*32 + (lane>>4)*8 + e][ct*16 + (lane&15)])
__global__ void prep_w(const float* __restrict__ wq, const float* __restrict__ wk,
                       const float* __restrict__ wv, const float* __restrict__ wo,
                       unsigned short* __restrict__ wt2) {
    int idx = blockIdx.x * 256 + threadIdx.x;   // 0..32767
    int lane = idx & 63;
    int kt   = (idx >> 6) & 7;
    int nt   = (idx >> 9) & 15;
    int m    = idx >> 13;
    const float* W = (m == 0) ? wq : (m == 1) ? wk : (m == 2) ? wv : wo;
    int g = lane & 15, uu = lane >> 4;
    int n = nt * 16 + g;
    unsigned short* dst = wt2 + (size_t)idx * 8;
    #pragma unroll
    for (int e = 0; e < 8; ++e) {
        int k = kt * 32 + uu * 8 + e;
        dst[e] = f2bf(W[k * 256 + n]);
    }
}

// 8 waves/block: wave = (half, head). Each wave has EXACTLY the R13 per-wave state
// (~108 arch VGPR at the 256-total budget of launch_bounds(...,2)) -> no spill.
// Block covers 32 positions -> per-CU L2 weight traffic halves vs R13.
__global__ __launch_bounds__(512, 2)
void fused_attn(const float* __restrict__ br0, const float* __restrict__ br1,
                const float* __restrict__ br2, const unsigned short* __restrict__ wt2,
                const float* __restrict__ bq, const float* __restrict__ bk,
                const float* __restrict__ bv, const float* __restrict__ bo,
                float* __restrict__ out) {
    // Xs: [96][256] bf16 swizzled (48 KB); Ys ([56][256] bf16, 28 KB) overlays the front.
    __shared__ char ldsb[49152];
    char* Xs = ldsb;
    char* Ys = ldsb;

    const int t    = threadIdx.x;
    const int wave = t >> 6;            // 0..7
    const int h    = wave & 3;          // head
    const int half = wave >> 2;         // position half (0: pos 0-15, 1: pos 16-31)
    const int lane = t & 63;
    const int g    = lane & 15;
    const int u    = lane >> 4;
    const int b    = blockIdx.x >> 7;   // 1024 blocks: 128 per batch
    const int l0   = (blockIdx.x & 127) << 5;   // 32 positions per block
    const int nb   = h * 64;            // head column base
    const int cc   = lane * 4;          // float column base
    const int rbase = half * 16;        // row offset within each 32-row branch block

    const s16x8* WF = (const s16x8*)wt2;

    // ---------------- phase 1: stage X (fused up-interp), bf16 swizzled ----------------
    // rows 0..31: br0 ; 32..63: br1 upsampled ; 64..95: br2 upsampled
    {
        #pragma unroll
        for (int it = 0; it < 12; ++it) {
            int r = it * 8 + wave;      // wave-uniform row (branch-uniform: 8 | 32)
            int n = r >> 5, p = r & 31;
            int l = l0 + p;
            float4 v;
            if (n == 0) {
                v = *(const float4*)(br0 + (size_t)(b * 4096 + l) * 256 + cc);
            } else {
                const float* src = (n == 1) ? br1 : br2;
                int   Lin   = (n == 1) ? 2048 : 1024;
                float scale = (n == 1) ? 0.5f : 0.25f;
                float sp = (l + 0.5f) * scale - 0.5f;
                sp = fminf(fmaxf(sp, 0.0f), (float)(Lin - 1));
                int i0 = (int)sp;
                int i1 = min(i0 + 1, Lin - 1);
                float w = sp - (float)i0;
                float4 a0 = *(const float4*)(src + (size_t)(b * Lin + i0) * 256 + cc);
                float4 a1 = *(const float4*)(src + (size_t)(b * Lin + i1) * 256 + cc);
                v.x = a0.x * (1.0f - w) + a1.x * w;
                v.y = a0.y * (1.0f - w) + a1.y * w;
                v.z = a0.z * (1.0f - w) + a1.z * w;
                v.w = a0.w * (1.0f - w) + a1.w * w;
            }
            u16x4 hv;
            hv.x = f2bf(v.x); hv.y = f2bf(v.y); hv.z = f2bf(v.z); hv.w = f2bf(v.w);
            *(u16x4*)(Xs + swz(r, cc)) = hv;
        }
    }
    __syncthreads();    // B1

    // ------- phase 2: Q+K projection, KT-OUTER (8 weight loads in flight per kt) -------
    float sc[3][3][4];                     // scores -> attention weights (in place)
    {
        f32x4 qc[4][3], kc[4][3];
        #pragma unroll
        for (int tc = 0; tc < 4; ++tc)
            #pragma unroll
            for (int n = 0; n < 3; ++n) {
                qc[tc][n] = (f32x4){0.f, 0.f, 0.f, 0.f};
                kc[tc][n] = (f32x4){0.f, 0.f, 0.f, 0.f};
            }

        __builtin_amdgcn_s_setprio(1);
        #pragma unroll
        for (int kt = 0; kt < 8; ++kt) {
            s16x8 a[3];
            #pragma unroll
            for (int n = 0; n < 3; ++n)
                a[n] = *(const s16x8*)(Xs + swz(n * 32 + rbase + g, kt * 32 + u * 8));
            s16x8 bfq[4], bfk[4];
            #pragma unroll
            for (int tc = 0; tc < 4; ++tc) {
                const int ct = h * 4 + tc;
                bfq[tc] = WF[((0 * 16 + ct) * 8 + kt) * 64 + lane];
                bfk[tc] = WF[((1 * 16 + ct) * 8 + kt) * 64 + lane];
            }
            #pragma unroll
            for (int tc = 0; tc < 4; ++tc)
                #pragma unroll
                for (int n = 0; n < 3; ++n) {
                    qc[tc][n] = __builtin_amdgcn_mfma_f32_16x16x32_bf16(a[n], bfq[tc], qc[tc][n], 0, 0, 0);
                    kc[tc][n] = __builtin_amdgcn_mfma_f32_16x16x32_bf16(a[n], bfk[tc], kc[tc][n], 0, 0, 0);
                }
        }
        __builtin_amdgcn_s_setprio(0);

        // scores: dot over the head's 64 dims = sum over tc (bias added per tc)
        #pragma unroll
        for (int n = 0; n < 3; ++n)
            #pragma unroll
            for (int m = 0; m < 3; ++m)
                #pragma unroll
                for (int j = 0; j < 4; ++j) sc[n][m][j] = 0.f;
        #pragma unroll
        for (int tc = 0; tc < 4; ++tc) {
            const float Bqv = bq[nb + tc * 16 + g];
            const float Bkv = bk[nb + tc * 16 + g];
            #pragma unroll
            for (int n = 0; n < 3; ++n)
                #pragma unroll
                for (int j = 0; j < 4; ++j) {
                    qc[tc][n][j] += Bqv;
                    kc[tc][n][j] += Bkv;
                }
            #pragma unroll
            for (int n = 0; n < 3; ++n)
                #pragma unroll
                for (int m = 0; m < 3; ++m)
                    #pragma unroll
                    for (int j = 0; j < 4; ++j)
                        sc[n][m][j] += qc[tc][n][j] * kc[tc][m][j];
        }
        // reduce over the 16 lanes (g) of each row group
        #pragma unroll
        for (int mask = 1; mask < 16; mask <<= 1)
            #pragma unroll
            for (int n = 0; n < 3; ++n)
                #pragma unroll
                for (int m = 0; m < 3; ++m)
                    #pragma unroll
                    for (int j = 0; j < 4; ++j)
                        sc[n][m][j] += __shfl_xor(sc[n][m][j], mask, 16);
        // softmax over m (scale 1/sqrt(64)), in place
        #pragma unroll
        for (int n = 0; n < 3; ++n)
            #pragma unroll
            for (int j = 0; j < 4; ++j) {
                float s0 = sc[n][0][j] * 0.125f;
                float s1 = sc[n][1][j] * 0.125f;
                float s2 = sc[n][2][j] * 0.125f;
                float mx = fmaxf(s0, fmaxf(s1, s2));
                float e0 = __expf(s0 - mx), e1 = __expf(s1 - mx), e2 = __expf(s2 - mx);
                float inv = 1.0f / (e0 + e1 + e2);
                sc[n][0][j] = e0 * inv;
                sc[n][1][j] = e1 * inv;
                sc[n][2][j] = e2 * inv;
            }
    }

    // ---------------- phase 3: V projection (kt-outer, 4 loads in flight) --------------
    f32x4 vacc[3][4];
    #pragma unroll
    for (int n = 0; n < 3; ++n)
        #pragma unroll
        for (int tc = 0; tc < 4; ++tc)
            vacc[n][tc] = (f32x4){0.f, 0.f, 0.f, 0.f};
    __builtin_amdgcn_s_setprio(1);
    #pragma unroll
    for (int kt = 0; kt < 8; ++kt) {
        s16x8 a[3];
        #pragma unroll
        for (int n = 0; n < 3; ++n)
            a[n] = *(const s16x8*)(Xs + swz(n * 32 + rbase + g, kt * 32 + u * 8));
        s16x8 bfv[4];
        #pragma unroll
        for (int tc = 0; tc < 4; ++tc)
            bfv[tc] = WF[((2 * 16 + h * 4 + tc) * 8 + kt) * 64 + lane];
        #pragma unroll
        for (int tc = 0; tc < 4; ++tc)
            #pragma unroll
            for (int n = 0; n < 3; ++n)
                vacc[n][tc] = __builtin_amdgcn_mfma_f32_16x16x32_bf16(a[n], bfv[tc], vacc[n][tc], 0, 0, 0);
    }
    __builtin_amdgcn_s_setprio(0);
    #pragma unroll
    for (int tc = 0; tc < 4; ++tc) {
        const float Bvv = bv[nb + tc * 16 + g];
        #pragma unroll
        for (int n = 0; n < 3; ++n)
            #pragma unroll
            for (int j = 0; j < 4; ++j)
                vacc[n][tc][j] += Bvv;
    }
    __syncthreads();    // B2: all X reads complete before overwriting Xs with O

    // ---------------- phase 4: O = attn @ V (per-lane), bf16 into Xs ----------------
    #pragma unroll
    for (int n = 0; n < 3; ++n)
        #pragma unroll
        for (int tc = 0; tc < 4; ++tc)
            #pragma unroll
            for (int j = 0; j < 4; ++j) {
                float o = sc[n][0][j] * vacc[0][tc][j] +
                          sc[n][1][j] * vacc[1][tc][j] +
                          sc[n][2][j] * vacc[2][tc][j];
                int row = n * 32 + rbase + u * 4 + j;
                *(unsigned short*)(Xs + swz(row, nb + tc * 16 + g)) = f2bf(o);
            }
    __syncthreads();    // B3: O complete before cross-head reads

    // ---------------- phase 5: output projection (kt-outer, 4 loads in flight) ---------
    f32x4 yacc[3][4];
    #pragma unroll
    for (int n = 0; n < 3; ++n)
        #pragma unroll
        for (int tc = 0; tc < 4; ++tc)
            yacc[n][tc] = (f32x4){0.f, 0.f, 0.f, 0.f};
    __builtin_amdgcn_s_setprio(1);
    #pragma unroll
    for (int kt = 0; kt < 8; ++kt) {
        s16x8 a[3];
        #pragma unroll
        for (int n = 0; n < 3; ++n)
            a[n] = *(const s16x8*)(Xs + swz(n * 32 + rbase + g, kt * 32 + u * 8));
        s16x8 bfo[4];
        #pragma unroll
        for (int tc = 0; tc < 4; ++tc)
            bfo[tc] = WF[((3 * 16 + h * 4 + tc) * 8 + kt) * 64 + lane];
        #pragma unroll
        for (int tc = 0; tc < 4; ++tc)
            #pragma unroll
            for (int n = 0; n < 3; ++n)
                yacc[n][tc] = __builtin_amdgcn_mfma_f32_16x16x32_bf16(a[n], bfo[tc], yacc[n][tc], 0, 0, 0);
    }
    __builtin_amdgcn_s_setprio(0);
    __syncthreads();    // B4: all O reads done; Ys may overlay the same LDS region

    // ------- phase 6: stage Y bf16 (bias + down-interp): [56][256] overlaying Xs -------
    // rows 0..31: branch0 ; 32..47: branch1 averaged ; 48..55: branch2 averaged
    #pragma unroll
    for (int tc = 0; tc < 4; ++tc) {
        int col = nb + tc * 16 + g;
        const float Bov = bo[col];
        #pragma unroll
        for (int j = 0; j < 4; ++j)
            *(unsigned short*)(Ys + swz(rbase + u * 4 + j, col)) =
                f2bf(yacc[0][tc][j] + Bov);
        #pragma unroll
        for (int jj = 0; jj < 2; ++jj)
            *(unsigned short*)(Ys + swz(32 + half * 8 + u * 2 + jj, col)) =
                f2bf(0.5f * (yacc[1][tc][2 * jj] + yacc[1][tc][2 * jj + 1]) + Bov);
        *(unsigned short*)(Ys + swz(48 + half * 4 + u, col)) =
            f2bf(0.5f * (yacc[2][tc][1] + yacc[2][tc][2]) + Bov);
    }
    __syncthreads();    // B5: Ys ready

    // ---------------- phase 7: coalesced f32x4 stores ----------------
    #pragma unroll
    for (int it = 0; it < 7; ++it) {
        int r = it * 8 + wave;          // wave-uniform row 0..55
        u16x4 hv = *(const u16x4*)(Ys + swz(r, cc));
        f32x4 v;
        v.x = bf2f(hv.x); v.y = bf2f(hv.y); v.z = bf2f(hv.z); v.w = bf2f(hv.w);
        float* dst;
        if (r < 32)      dst = out + (size_t)(b * 4096 + l0 + r) * 256 + cc;
        else if (r < 48) dst = out + 8388608 + (size_t)(b * 2048 + (l0 >> 1) + (r - 32)) * 256 + cc;
        else             dst = out + 12582912 + (size_t)(b * 1024 + (l0 >> 2) + (r - 48)) * 256 + cc;
        *(f32x4*)dst = v;
    }
}

extern "C" void kernel_launch(void* const* d_in, const int* in_sizes, int n_in,
                              void* d_out, int out_size, void* d_ws, size_t ws_size,
                              hipStream_t stream) {
    const float* br0 = (const float*)d_in[0];
    const float* br1 = (const float*)d_in[1];
    const float* br2 = (const float*)d_in[2];
    const float* Wq  = (const float*)d_in[3];
    const float* bq  = (const float*)d_in[4];
    const float* Wk  = (const float*)d_in[5];
    const float* bk  = (const float*)d_in[6];
    const float* Wv  = (const float*)d_in[7];
    const float* bv  = (const float*)d_in[8];
    const float* Wo  = (const float*)d_in[9];
    const float* bo  = (const float*)d_in[10];

    unsigned short* wt2 = (unsigned short*)d_ws;  // 4*256*256 bf16 = 512 KB, fragment order

    prep_w<<<128, 256, 0, stream>>>(Wq, Wk, Wv, Wo, wt2);
    fused_attn<<<1024, 512, 0, stream>>>(br0, br1, br2, wt2, bq, bk, bv, bo,
                                         (float*)d_out);
}

// Round 17
// 114.118 us; speedup vs baseline: 4.5637x; 1.0298x over previous
//
#include <hip/hip_runtime.h>

typedef __attribute__((ext_vector_type(4))) float f32x4;
typedef __attribute__((ext_vector_type(8))) short s16x8;
typedef __attribute__((ext_vector_type(4))) unsigned short u16x4;

__device__ __forceinline__ unsigned short f2bf(float f) {
    union { float f; unsigned int u; } v; v.f = f;
    unsigned int r = v.u + 0x7fffu + ((v.u >> 16) & 1u);
    return (unsigned short)(r >> 16);
}
// byte offset into a [48][256] bf16 LDS tile, XOR-swizzled (row stride 512B)
__device__ __forceinline__ unsigned int swz(int row, int col) {
    return (unsigned int)(row * 512 + col * 2) ^ (((unsigned int)row & 7u) << 4);
}
// byte offset into a [28][256] f32 LDS tile, XOR-swizzled (row stride 1024B)
__device__ __forceinline__ unsigned int swz32(int row, int col) {
    return (unsigned int)(row * 1024 + col * 4) ^ (((unsigned int)row & 7u) << 4);
}

// Weights pre-packed in MFMA B-fragment order:
// wt2[m][ct][kt][lane][e] = bf16(W_m[kt*32 + (lane>>4)*8 + e][ct*16 + (lane&15)])
__global__ void prep_w(const float* __restrict__ wq, const float* __restrict__ wk,
                       const float* __restrict__ wv, const float* __restrict__ wo,
                       unsigned short* __restrict__ wt2) {
    int idx = blockIdx.x * 256 + threadIdx.x;   // 0..32767
    int lane = idx & 63;
    int kt   = (idx >> 6) & 7;
    int nt   = (idx >> 9) & 15;
    int m    = idx >> 13;
    const float* W = (m == 0) ? wq : (m == 1) ? wk : (m == 2) ? wv : wo;
    int g = lane & 15, uu = lane >> 4;
    int n = nt * 16 + g;
    unsigned short* dst = wt2 + (size_t)idx * 8;
    #pragma unroll
    for (int e = 0; e < 8; ++e) {
        int k = kt * 32 + uu * 8 + e;
        dst[e] = f2bf(W[k * 256 + n]);
    }
}

// 53248 B LDS (Xs 24K + Ys 28K) and ~148 total regs/wave -> 3 blocks/CU, 12 waves/CU.
__global__ __launch_bounds__(256, 3)
void fused_attn(const float* __restrict__ br0, const float* __restrict__ br1,
                const float* __restrict__ br2, const unsigned short* __restrict__ wt2,
                const float* __restrict__ bq, const float* __restrict__ bk,
                const float* __restrict__ bv, const float* __restrict__ bo,
                float* __restrict__ out) {
    // Xs: [0, 24576) bf16 X / later O. Ys: [24576, 53248) f32 staged output (no alias).
    __shared__ char ldsb[53248];
    char* Xs = ldsb;
    char* Ys = ldsb + 24576;

    const int t    = threadIdx.x;
    const int wave = t >> 6;            // = head index
    const int lane = t & 63;
    const int g    = lane & 15;
    const int u    = lane >> 4;
    const int b    = blockIdx.x >> 8;
    const int l0   = (blockIdx.x & 255) << 4;
    const int nb   = wave * 64;         // head column base
    const int cc   = lane * 4;

    const s16x8* WF = (const s16x8*)wt2;   // fragment-ordered weights

    // ---------------- phase 1: stage X (fused up-interp), bf16 swizzled ----------------
    {
        #pragma unroll
        for (int it = 0; it < 12; ++it) {
            int r = it * 4 + wave;      // wave-uniform row
            int n = r >> 4, p = r & 15;
            int l = l0 + p;
            float4 v;
            if (n == 0) {
                v = *(const float4*)(br0 + (size_t)(b * 4096 + l) * 256 + cc);
            } else {
                const float* src = (n == 1) ? br1 : br2;
                int   Lin   = (n == 1) ? 2048 : 1024;
                float scale = (n == 1) ? 0.5f : 0.25f;
                float sp = (l + 0.5f) * scale - 0.5f;
                sp = fminf(fmaxf(sp, 0.0f), (float)(Lin - 1));
                int i0 = (int)sp;
                int i1 = min(i0 + 1, Lin - 1);
                float w = sp - (float)i0;
                float4 a0 = *(const float4*)(src + (size_t)(b * Lin + i0) * 256 + cc);
                float4 a1 = *(const float4*)(src + (size_t)(b * Lin + i1) * 256 + cc);
                v.x = a0.x * (1.0f - w) + a1.x * w;
                v.y = a0.y * (1.0f - w) + a1.y * w;
                v.z = a0.z * (1.0f - w) + a1.z * w;
                v.w = a0.w * (1.0f - w) + a1.w * w;
            }
            u16x4 h;
            h.x = f2bf(v.x); h.y = f2bf(v.y); h.z = f2bf(v.z); h.w = f2bf(v.w);
            *(u16x4*)(Xs + swz(r, cc)) = h;
        }
    }
    __syncthreads();                                    // B1

    // ------- phase 2: Q+K projection in TWO tc-halves (48 acc regs live, not 96) -------
    float sc[3][3][4];                     // scores -> attention weights (in place)
    {
        #pragma unroll
        for (int n = 0; n < 3; ++n)
            #pragma unroll
            for (int m = 0; m < 3; ++m)
                #pragma unroll
                for (int j = 0; j < 4; ++j) sc[n][m][j] = 0.f;

        #pragma unroll
        for (int hg = 0; hg < 2; ++hg) {       // half-group: tc = hg*2 + {0,1}
            f32x4 qc[2][3], kc[2][3];
            #pragma unroll
            for (int tc = 0; tc < 2; ++tc)
                #pragma unroll
                for (int n = 0; n < 3; ++n) {
                    qc[tc][n] = (f32x4){0.f, 0.f, 0.f, 0.f};
                    kc[tc][n] = (f32x4){0.f, 0.f, 0.f, 0.f};
                }

            __builtin_amdgcn_s_setprio(1);
            #pragma unroll
            for (int kt = 0; kt < 8; ++kt) {
                s16x8 a[3];
                #pragma unroll
                for (int n = 0; n < 3; ++n)
                    a[n] = *(const s16x8*)(Xs + swz(n * 16 + g, kt * 32 + u * 8));
                s16x8 bfq[2], bfk[2];
                #pragma unroll
                for (int tc = 0; tc < 2; ++tc) {
                    const int ct = wave * 4 + hg * 2 + tc;
                    bfq[tc] = WF[((0 * 16 + ct) * 8 + kt) * 64 + lane];
                    bfk[tc] = WF[((1 * 16 + ct) * 8 + kt) * 64 + lane];
                }
                #pragma unroll
                for (int tc = 0; tc < 2; ++tc)
                    #pragma unroll
                    for (int n = 0; n < 3; ++n) {
                        qc[tc][n] = __builtin_amdgcn_mfma_f32_16x16x32_bf16(a[n], bfq[tc], qc[tc][n], 0, 0, 0);
                        kc[tc][n] = __builtin_amdgcn_mfma_f32_16x16x32_bf16(a[n], bfk[tc], kc[tc][n], 0, 0, 0);
                    }
            }
            __builtin_amdgcn_s_setprio(0);

            // bias + partial score dot for this half
            #pragma unroll
            for (int tc = 0; tc < 2; ++tc) {
                const int col = nb + (hg * 2 + tc) * 16 + g;
                const float Bqv = bq[col];
                const float Bkv = bk[col];
                #pragma unroll
                for (int n = 0; n < 3; ++n)
                    #pragma unroll
                    for (int j = 0; j < 4; ++j) {
                        qc[tc][n][j] += Bqv;
                        kc[tc][n][j] += Bkv;
                    }
                #pragma unroll
                for (int n = 0; n < 3; ++n)
                    #pragma unroll
                    for (int m = 0; m < 3; ++m)
                        #pragma unroll
                        for (int j = 0; j < 4; ++j)
                            sc[n][m][j] += qc[tc][n][j] * kc[tc][m][j];
            }
        }
        // reduce over the 16 lanes (g) of each row group
        #pragma unroll
        for (int mask = 1; mask < 16; mask <<= 1)
            #pragma unroll
            for (int n = 0; n < 3; ++n)
                #pragma unroll
                for (int m = 0; m < 3; ++m)
                    #pragma unroll
                    for (int j = 0; j < 4; ++j)
                        sc[n][m][j] += __shfl_xor(sc[n][m][j], mask, 16);
        // softmax over m (scale 1/sqrt(64)), in place
        #pragma unroll
        for (int n = 0; n < 3; ++n)
            #pragma unroll
            for (int j = 0; j < 4; ++j) {
                float s0 = sc[n][0][j] * 0.125f;
                float s1 = sc[n][1][j] * 0.125f;
                float s2 = sc[n][2][j] * 0.125f;
                float mx = fmaxf(s0, fmaxf(s1, s2));
                float e0 = __expf(s0 - mx), e1 = __expf(s1 - mx), e2 = __expf(s2 - mx);
                float inv = 1.0f / (e0 + e1 + e2);
                sc[n][0][j] = e0 * inv;
                sc[n][1][j] = e1 * inv;
                sc[n][2][j] = e2 * inv;
            }
    }

    // ---------------- phase 3: V projection (kt-outer, 4 loads in flight) --------------
    f32x4 vacc[3][4];
    #pragma unroll
    for (int n = 0; n < 3; ++n)
        #pragma unroll
        for (int tc = 0; tc < 4; ++tc)
            vacc[n][tc] = (f32x4){0.f, 0.f, 0.f, 0.f};
    __builtin_amdgcn_s_setprio(1);
    #pragma unroll
    for (int kt = 0; kt < 8; ++kt) {
        s16x8 a[3];
        #pragma unroll
        for (int n = 0; n < 3; ++n)
            a[n] = *(const s16x8*)(Xs + swz(n * 16 + g, kt * 32 + u * 8));
        s16x8 bfv[4];
        #pragma unroll
        for (int tc = 0; tc < 4; ++tc)
            bfv[tc] = WF[((2 * 16 + wave * 4 + tc) * 8 + kt) * 64 + lane];
        #pragma unroll
        for (int tc = 0; tc < 4; ++tc)
            #pragma unroll
            for (int n = 0; n < 3; ++n)
                vacc[n][tc] = __builtin_amdgcn_mfma_f32_16x16x32_bf16(a[n], bfv[tc], vacc[n][tc], 0, 0, 0);
    }
    __builtin_amdgcn_s_setprio(0);
    #pragma unroll
    for (int tc = 0; tc < 4; ++tc) {
        const float Bvv = bv[nb + tc * 16 + g];
        #pragma unroll
        for (int n = 0; n < 3; ++n)
            #pragma unroll
            for (int j = 0; j < 4; ++j)
                vacc[n][tc][j] += Bvv;
    }
    __syncthreads();    // B2: all X reads complete before overwriting Xs with O

    // ---------------- phase 4: O = attn @ V (per-lane), write bf16 to Xs ---------------
    #pragma unroll
    for (int n = 0; n < 3; ++n)
        #pragma unroll
        for (int tc = 0; tc < 4; ++tc)
            #pragma unroll
            for (int j = 0; j < 4; ++j) {
                float o = sc[n][0][j] * vacc[0][tc][j] +
                          sc[n][1][j] * vacc[1][tc][j] +
                          sc[n][2][j] * vacc[2][tc][j];
                *(unsigned short*)(Xs + swz(n * 16 + u * 4 + j, nb + tc * 16 + g)) = f2bf(o);
            }
    __syncthreads();    // B3: O complete before cross-head reads

    // ---------------- phase 5: output projection (kt-outer, 4 loads in flight) ---------
    f32x4 yacc[3][4];
    #pragma unroll
    for (int n = 0; n < 3; ++n)
        #pragma unroll
        for (int tc = 0; tc < 4; ++tc)
            yacc[n][tc] = (f32x4){0.f, 0.f, 0.f, 0.f};
    __builtin_amdgcn_s_setprio(1);
    #pragma unroll
    for (int kt = 0; kt < 8; ++kt) {
        s16x8 a[3];
        #pragma unroll
        for (int n = 0; n < 3; ++n)
            a[n] = *(const s16x8*)(Xs + swz(n * 16 + g, kt * 32 + u * 8));
        s16x8 bfo[4];
        #pragma unroll
        for (int tc = 0; tc < 4; ++tc)
            bfo[tc] = WF[((3 * 16 + wave * 4 + tc) * 8 + kt) * 64 + lane];
        #pragma unroll
        for (int tc = 0; tc < 4; ++tc)
            #pragma unroll
            for (int n = 0; n < 3; ++n)
                yacc[n][tc] = __builtin_amdgcn_mfma_f32_16x16x32_bf16(a[n], bfo[tc], yacc[n][tc], 0, 0, 0);
    }
    __builtin_amdgcn_s_setprio(0);

    // ---------------- phase 6: stage Y (bias + down-interp) into LDS f32 (no alias) ----
    #pragma unroll
    for (int tc = 0; tc < 4; ++tc) {
        int col = nb + tc * 16 + g;
        const float Bov = bo[col];
        #pragma unroll
        for (int j = 0; j < 4; ++j)
            *(float*)(Ys + swz32(u * 4 + j, col)) = yacc[0][tc][j] + Bov;
        #pragma unroll
        for (int jj = 0; jj < 2; ++jj)
            *(float*)(Ys + swz32(16 + u * 2 + jj, col)) =
                0.5f * (yacc[1][tc][2 * jj] + yacc[1][tc][2 * jj + 1]) + Bov;
        *(float*)(Ys + swz32(24 + u, col)) =
            0.5f * (yacc[2][tc][1] + yacc[2][tc][2]) + Bov;
    }
    __syncthreads();    // B4

    // ---------------- phase 7: coalesced f32x4 stores ----------------
    {
        // branch0: 16 rows
        #pragma unroll
        for (int it = 0; it < 4; ++it) {
            int r = it * 4 + wave;
            f32x4 v = *(const f32x4*)(Ys + swz32(r, cc));
            *(f32x4*)(out + (size_t)(b * 4096 + l0 + r) * 256 + cc) = v;
        }
        // branch1: 8 rows
        #pragma unroll
        for (int it = 0; it < 2; ++it) {
            int q = it * 4 + wave;
            f32x4 v = *(const f32x4*)(Ys + swz32(16 + q, cc));
            *(f32x4*)(out + 8388608 + (size_t)(b * 2048 + (l0 >> 1) + q) * 256 + cc) = v;
        }
        // branch2: 4 rows
        {
            f32x4 v = *(const f32x4*)(Ys + swz32(24 + wave, cc));
            *(f32x4*)(out + 12582912 + (size_t)(b * 1024 + (l0 >> 2) + wave) * 256 + cc) = v;
        }
    }
}

extern "C" void kernel_launch(void* const* d_in, const int* in_sizes, int n_in,
                              void* d_out, int out_size, void* d_ws, size_t ws_size,
                              hipStream_t stream) {
    const float* br0 = (const float*)d_in[0];
    const float* br1 = (const float*)d_in[1];
    const float* br2 = (const float*)d_in[2];
    const float* Wq  = (const float*)d_in[3];
    const float* bq  = (const float*)d_in[4];
    const float* Wk  = (const float*)d_in[5];
    const float* bk  = (const float*)d_in[6];
    const float* Wv  = (const float*)d_in[7];
    const float* bv  = (const float*)d_in[8];
    const float* Wo  = (const float*)d_in[9];
    const float* bo  = (const float*)d_in[10];

    unsigned short* wt2 = (unsigned short*)d_ws;  // 4*256*256 bf16 = 512 KB, fragment order

    prep_w<<<128, 256, 0, stream>>>(Wq, Wk, Wv, Wo, wt2);
    fused_attn<<<2048, 256, 0, stream>>>(br0, br1, br2, wt2, bq, bk, bv, bo,
                                         (float*)d_out);
}

// Round 18
// 104.979 us; speedup vs baseline: 4.9610x; 1.0871x over previous
//
#include <hip/hip_runtime.h>

typedef __attribute__((ext_vector_type(4))) float f32x4;
typedef __attribute__((ext_vector_type(8))) short s16x8;
typedef __attribute__((ext_vector_type(4))) unsigned short u16x4;

__device__ __forceinline__ unsigned short f2bf(float f) {
    union { float f; unsigned int u; } v; v.f = f;
    unsigned int r = v.u + 0x7fffu + ((v.u >> 16) & 1u);
    return (unsigned short)(r >> 16);
}
// byte offset into a [rows][256] bf16 LDS tile, XOR-swizzled (row stride 512B)
__device__ __forceinline__ unsigned int swz(int row, int col) {
    return (unsigned int)(row * 512 + col * 2) ^ (((unsigned int)row & 7u) << 4);
}
// byte offset into a [28][256] f32 LDS tile, XOR-swizzled (row stride 1024B)
__device__ __forceinline__ unsigned int swz32(int row, int col) {
    return (unsigned int)(row * 1024 + col * 4) ^ (((unsigned int)row & 7u) << 4);
}
// one butterfly stage over 16-lane groups via ds_swizzle (BitMode, and=0x1F, xor=mask)
#define SWZ_ADD(x, pat)                                                        \
    do {                                                                       \
        union { float f; int i; } _v; _v.f = (x);                              \
        _v.i = __builtin_amdgcn_ds_swizzle(_v.i, (pat));                       \
        (x) += _v.f;                                                           \
    } while (0)

// Weights pre-packed in MFMA B-fragment order:
// wt2[m][ct][kt][lane][e] = bf16(W_m[kt*32 + (lane>>4)*8 + e][ct*16 + (lane&15)])
__global__ void prep_w(const float* __restrict__ wq, const float* __restrict__ wk,
                       const float* __restrict__ wv, const float* __restrict__ wo,
                       unsigned short* __restrict__ wt2) {
    int idx = blockIdx.x * 256 + threadIdx.x;   // 0..32767
    int lane = idx & 63;
    int kt   = (idx >> 6) & 7;
    int nt   = (idx >> 9) & 15;
    int m    = idx >> 13;
    const float* W = (m == 0) ? wq : (m == 1) ? wk : (m == 2) ? wv : wo;
    int g = lane & 15, uu = lane >> 4;
    int n = nt * 16 + g;
    unsigned short* dst = wt2 + (size_t)idx * 8;
    #pragma unroll
    for (int e = 0; e < 8; ++e) {
        int k = kt * 32 + uu * 8 + e;
        dst[e] = f2bf(W[k * 256 + n]);
    }
}

__global__ __launch_bounds__(256, 2)
void fused_attn(const float* __restrict__ br0, const float* __restrict__ br1,
                const float* __restrict__ br2, const unsigned short* __restrict__ wt2,
                const float* __restrict__ bq, const float* __restrict__ bk,
                const float* __restrict__ bv, const float* __restrict__ bo,
                float* __restrict__ out) {
    // Xs: [0, 24576) bf16 X (never overwritten -> no X/O barrier).
    // Os: [32768, 57344) bf16 O [48][256]; Ys f32 [28][256] overlays [32768, 61440)
    // after all O reads complete. 61440B -> 2 blocks/CU (weight-L2-residency regime).
    __shared__ char ldsb[61440];
    char* Xs = ldsb;
    char* Os = ldsb + 32768;
    char* Ys = ldsb + 32768;

    const int t    = threadIdx.x;
    const int wave = t >> 6;            // = head index
    const int lane = t & 63;
    const int g    = lane & 15;
    const int u    = lane >> 4;
    const int b    = blockIdx.x >> 8;
    const int l0   = (blockIdx.x & 255) << 4;
    const int nb   = wave * 64;         // head column base
    const int cc   = lane * 4;

    const s16x8* WF = (const s16x8*)wt2;   // fragment-ordered weights

    // ---------------- phase 1: stage X (fused up-interp), bf16 swizzled ----------------
    {
        #pragma unroll
        for (int it = 0; it < 12; ++it) {
            int r = it * 4 + wave;      // wave-uniform row
            int n = r >> 4, p = r & 15;
            int l = l0 + p;
            float4 v;
            if (n == 0) {
                v = *(const float4*)(br0 + (size_t)(b * 4096 + l) * 256 + cc);
            } else {
                const float* src = (n == 1) ? br1 : br2;
                int   Lin   = (n == 1) ? 2048 : 1024;
                float scale = (n == 1) ? 0.5f : 0.25f;
                float sp = (l + 0.5f) * scale - 0.5f;
                sp = fminf(fmaxf(sp, 0.0f), (float)(Lin - 1));
                int i0 = (int)sp;
                int i1 = min(i0 + 1, Lin - 1);
                float w = sp - (float)i0;
                float4 a0 = *(const float4*)(src + (size_t)(b * Lin + i0) * 256 + cc);
                float4 a1 = *(const float4*)(src + (size_t)(b * Lin + i1) * 256 + cc);
                v.x = a0.x * (1.0f - w) + a1.x * w;
                v.y = a0.y * (1.0f - w) + a1.y * w;
                v.z = a0.z * (1.0f - w) + a1.z * w;
                v.w = a0.w * (1.0f - w) + a1.w * w;
            }
            u16x4 h;
            h.x = f2bf(v.x); h.y = f2bf(v.y); h.z = f2bf(v.z); h.w = f2bf(v.w);
            *(u16x4*)(Xs + swz(r, cc)) = h;
        }
    }
    __syncthreads();                                    // B1: X staged

    // ------- phase 2: Q+K projection, KT-OUTER (8 weight loads in flight per kt) -------
    float sc[3][3][4];                     // scores -> attention weights (in place)
    {
        f32x4 qc[4][3], kc[4][3];
        #pragma unroll
        for (int tc = 0; tc < 4; ++tc)
            #pragma unroll
            for (int n = 0; n < 3; ++n) {
                qc[tc][n] = (f32x4){0.f, 0.f, 0.f, 0.f};
                kc[tc][n] = (f32x4){0.f, 0.f, 0.f, 0.f};
            }

        __builtin_amdgcn_s_setprio(1);
        #pragma unroll
        for (int kt = 0; kt < 8; ++kt) {
            s16x8 a[3];
            #pragma unroll
            for (int n = 0; n < 3; ++n)
                a[n] = *(const s16x8*)(Xs + swz(n * 16 + g, kt * 32 + u * 8));
            s16x8 bfq[4], bfk[4];
            #pragma unroll
            for (int tc = 0; tc < 4; ++tc) {
                const int ct = wave * 4 + tc;
                bfq[tc] = WF[((0 * 16 + ct) * 8 + kt) * 64 + lane];
                bfk[tc] = WF[((1 * 16 + ct) * 8 + kt) * 64 + lane];
            }
            #pragma unroll
            for (int tc = 0; tc < 4; ++tc)
                #pragma unroll
                for (int n = 0; n < 3; ++n) {
                    qc[tc][n] = __builtin_amdgcn_mfma_f32_16x16x32_bf16(a[n], bfq[tc], qc[tc][n], 0, 0, 0);
                    kc[tc][n] = __builtin_amdgcn_mfma_f32_16x16x32_bf16(a[n], bfk[tc], kc[tc][n], 0, 0, 0);
                }
        }
        __builtin_amdgcn_s_setprio(0);

        // scores: dot over the head's 64 dims = sum over tc (bias added per tc)
        #pragma unroll
        for (int n = 0; n < 3; ++n)
            #pragma unroll
            for (int m = 0; m < 3; ++m)
                #pragma unroll
                for (int j = 0; j < 4; ++j) sc[n][m][j] = 0.f;
        #pragma unroll
        for (int tc = 0; tc < 4; ++tc) {
            const float Bqv = bq[nb + tc * 16 + g];
            const float Bkv = bk[nb + tc * 16 + g];
            #pragma unroll
            for (int n = 0; n < 3; ++n)
                #pragma unroll
                for (int j = 0; j < 4; ++j) {
                    qc[tc][n][j] += Bqv;
                    kc[tc][n][j] += Bkv;
                }
            #pragma unroll
            for (int n = 0; n < 3; ++n)
                #pragma unroll
                for (int m = 0; m < 3; ++m)
                    #pragma unroll
                    for (int j = 0; j < 4; ++j)
                        sc[n][m][j] += qc[tc][n][j] * kc[tc][m][j];
        }
        // butterfly reduce over the 16 lanes (g) of each row group, via ds_swizzle
        #pragma unroll
        for (int n = 0; n < 3; ++n)
            #pragma unroll
            for (int m = 0; m < 3; ++m)
                #pragma unroll
                for (int j = 0; j < 4; ++j) {
                    SWZ_ADD(sc[n][m][j], 0x041F);   // xor 1
                    SWZ_ADD(sc[n][m][j], 0x081F);   // xor 2
                    SWZ_ADD(sc[n][m][j], 0x101F);   // xor 4
                    SWZ_ADD(sc[n][m][j], 0x201F);   // xor 8
                }
        // softmax over m (scale 1/sqrt(64)), in place
        #pragma unroll
        for (int n = 0; n < 3; ++n)
            #pragma unroll
            for (int j = 0; j < 4; ++j) {
                float s0 = sc[n][0][j] * 0.125f;
                float s1 = sc[n][1][j] * 0.125f;
                float s2 = sc[n][2][j] * 0.125f;
                float mx = fmaxf(s0, fmaxf(s1, s2));
                float e0 = __expf(s0 - mx), e1 = __expf(s1 - mx), e2 = __expf(s2 - mx);
                float inv = 1.0f / (e0 + e1 + e2);
                sc[n][0][j] = e0 * inv;
                sc[n][1][j] = e1 * inv;
                sc[n][2][j] = e2 * inv;
            }
    }

    // ---------------- phase 3: V projection (kt-outer, 4 loads in flight) --------------
    f32x4 vacc[3][4];
    #pragma unroll
    for (int n = 0; n < 3; ++n)
        #pragma unroll
        for (int tc = 0; tc < 4; ++tc)
            vacc[n][tc] = (f32x4){0.f, 0.f, 0.f, 0.f};
    __builtin_amdgcn_s_setprio(1);
    #pragma unroll
    for (int kt = 0; kt < 8; ++kt) {
        s16x8 a[3];
        #pragma unroll
        for (int n = 0; n < 3; ++n)
            a[n] = *(const s16x8*)(Xs + swz(n * 16 + g, kt * 32 + u * 8));
        s16x8 bfv[4];
        #pragma unroll
        for (int tc = 0; tc < 4; ++tc)
            bfv[tc] = WF[((2 * 16 + wave * 4 + tc) * 8 + kt) * 64 + lane];
        #pragma unroll
        for (int tc = 0; tc < 4; ++tc)
            #pragma unroll
            for (int n = 0; n < 3; ++n)
                vacc[n][tc] = __builtin_amdgcn_mfma_f32_16x16x32_bf16(a[n], bfv[tc], vacc[n][tc], 0, 0, 0);
    }
    __builtin_amdgcn_s_setprio(0);
    #pragma unroll
    for (int tc = 0; tc < 4; ++tc) {
        const float Bvv = bv[nb + tc * 16 + g];
        #pragma unroll
        for (int n = 0; n < 3; ++n)
            #pragma unroll
            for (int j = 0; j < 4; ++j)
                vacc[n][tc][j] += Bvv;
    }
    // NO barrier here: O goes to Os (separate region), X stays intact.

    // ---------------- phase 4: O = attn @ V (per-lane), write bf16 to Os ---------------
    #pragma unroll
    for (int n = 0; n < 3; ++n)
        #pragma unroll
        for (int tc = 0; tc < 4; ++tc)
            #pragma unroll
            for (int j = 0; j < 4; ++j) {
                float o = sc[n][0][j] * vacc[0][tc][j] +
                          sc[n][1][j] * vacc[1][tc][j] +
                          sc[n][2][j] * vacc[2][tc][j];
                *(unsigned short*)(Os + swz(n * 16 + u * 4 + j, nb + tc * 16 + g)) = f2bf(o);
            }
    __syncthreads();    // B2: O complete before cross-head reads

    // ---------------- phase 5: output projection (kt-outer, 4 loads in flight) ---------
    f32x4 yacc[3][4];
    #pragma unroll
    for (int n = 0; n < 3; ++n)
        #pragma unroll
        for (int tc = 0; tc < 4; ++tc)
            yacc[n][tc] = (f32x4){0.f, 0.f, 0.f, 0.f};
    __builtin_amdgcn_s_setprio(1);
    #pragma unroll
    for (int kt = 0; kt < 8; ++kt) {
        s16x8 a[3];
        #pragma unroll
        for (int n = 0; n < 3; ++n)
            a[n] = *(const s16x8*)(Os + swz(n * 16 + g, kt * 32 + u * 8));
        s16x8 bfo[4];
        #pragma unroll
        for (int tc = 0; tc < 4; ++tc)
            bfo[tc] = WF[((3 * 16 + wave * 4 + tc) * 8 + kt) * 64 + lane];
        #pragma unroll
        for (int tc = 0; tc < 4; ++tc)
            #pragma unroll
            for (int n = 0; n < 3; ++n)
                yacc[n][tc] = __builtin_amdgcn_mfma_f32_16x16x32_bf16(a[n], bfo[tc], yacc[n][tc], 0, 0, 0);
    }
    __builtin_amdgcn_s_setprio(0);
    __syncthreads();    // B3: all O reads done; Ys may overlay the Os region

    // ---------------- phase 6: stage Y (bias + down-interp) into LDS f32 ----------------
    // rows 0..15: branch0 ; 16..23: branch1 averaged ; 24..27: branch2 averaged
    #pragma unroll
    for (int tc = 0; tc < 4; ++tc) {
        int col = nb + tc * 16 + g;
        const float Bov = bo[col];
        #pragma unroll
        for (int j = 0; j < 4; ++j)
            *(float*)(Ys + swz32(u * 4 + j, col)) = yacc[0][tc][j] + Bov;
        #pragma unroll
        for (int jj = 0; jj < 2; ++jj)
            *(float*)(Ys + swz32(16 + u * 2 + jj, col)) =
                0.5f * (yacc[1][tc][2 * jj] + yacc[1][tc][2 * jj + 1]) + Bov;
        *(float*)(Ys + swz32(24 + u, col)) =
            0.5f * (yacc[2][tc][1] + yacc[2][tc][2]) + Bov;
    }
    __syncthreads();    // B4: Ys ready

    // ---------------- phase 7: coalesced f32x4 stores ----------------
    {
        // branch0: 16 rows
        #pragma unroll
        for (int it = 0; it < 4; ++it) {
            int r = it * 4 + wave;
            f32x4 v = *(const f32x4*)(Ys + swz32(r, cc));
            *(f32x4*)(out + (size_t)(b * 4096 + l0 + r) * 256 + cc) = v;
        }
        // branch1: 8 rows
        #pragma unroll
        for (int it = 0; it < 2; ++it) {
            int q = it * 4 + wave;
            f32x4 v = *(const f32x4*)(Ys + swz32(16 + q, cc));
            *(f32x4*)(out + 8388608 + (size_t)(b * 2048 + (l0 >> 1) + q) * 256 + cc) = v;
        }
        // branch2: 4 rows
        {
            f32x4 v = *(const f32x4*)(Ys + swz32(24 + wave, cc));
            *(f32x4*)(out + 12582912 + (size_t)(b * 1024 + (l0 >> 2) + wave) * 256 + cc) = v;
        }
    }
}

extern "C" void kernel_launch(void* const* d_in, const int* in_sizes, int n_in,
                              void* d_out, int out_size, void* d_ws, size_t ws_size,
                              hipStream_t stream) {
    const float* br0 = (const float*)d_in[0];
    const float* br1 = (const float*)d_in[1];
    const float* br2 = (const float*)d_in[2];
    const float* Wq  = (const float*)d_in[3];
    const float* bq  = (const float*)d_in[4];
    const float* Wk  = (const float*)d_in[5];
    const float* bk  = (const float*)d_in[6];
    const float* Wv  = (const float*)d_in[7];
    const float* bv  = (const float*)d_in[8];
    const float* Wo  = (const float*)d_in[9];
    const float* bo  = (const float*)d_in[10];

    unsigned short* wt2 = (unsigned short*)d_ws;  // 4*256*256 bf16 = 512 KB, fragment order

    prep_w<<<128, 256, 0, stream>>>(Wq, Wk, Wv, Wo, wt2);
    fused_attn<<<2048, 256, 0, stream>>>(br0, br1, br2, wt2, bq, bk, bv, bo,
                                         (float*)d_out);
}

// Round 19
// 100.574 us; speedup vs baseline: 5.1783x; 1.0438x over previous
//
#include <hip/hip_runtime.h>

typedef __attribute__((ext_vector_type(4))) float f32x4;
typedef __attribute__((ext_vector_type(8))) short s16x8;
typedef __attribute__((ext_vector_type(4))) unsigned short u16x4;

__device__ __forceinline__ unsigned short f2bf(float f) {
    union { float f; unsigned int u; } v; v.f = f;
    unsigned int r = v.u + 0x7fffu + ((v.u >> 16) & 1u);
    return (unsigned short)(r >> 16);
}
// byte offset into a [rows][256] bf16 LDS tile, XOR-swizzled (row stride 512B)
__device__ __forceinline__ unsigned int swz(int row, int col) {
    return (unsigned int)(row * 512 + col * 2) ^ (((unsigned int)row & 7u) << 4);
}
// byte offset into a [28][256] f32 LDS tile, XOR-swizzled (row stride 1024B)
__device__ __forceinline__ unsigned int swz32(int row, int col) {
    return (unsigned int)(row * 1024 + col * 4) ^ (((unsigned int)row & 7u) << 4);
}
// one butterfly stage over 16-lane groups via ds_swizzle (BitMode, and=0x1F, xor=mask)
#define SWZ_ADD(x, pat)                                                        \
    do {                                                                       \
        union { float f; int i; } _v; _v.f = (x);                              \
        _v.i = __builtin_amdgcn_ds_swizzle(_v.i, (pat));                       \
        (x) += _v.f;                                                           \
    } while (0)

// Weights pre-packed in MFMA B-fragment order:
// wt2[m][ct][kt][lane][e] = bf16(W_m[kt*32 + (lane>>4)*8 + e][ct*16 + (lane&15)])
__global__ void prep_w(const float* __restrict__ wq, const float* __restrict__ wk,
                       const float* __restrict__ wv, const float* __restrict__ wo,
                       unsigned short* __restrict__ wt2) {
    int idx = blockIdx.x * 256 + threadIdx.x;   // 0..32767
    int lane = idx & 63;
    int kt   = (idx >> 6) & 7;
    int nt   = (idx >> 9) & 15;
    int m    = idx >> 13;
    const float* W = (m == 0) ? wq : (m == 1) ? wk : (m == 2) ? wv : wo;
    int g = lane & 15, uu = lane >> 4;
    int n = nt * 16 + g;
    unsigned short* dst = wt2 + (size_t)idx * 8;
    #pragma unroll
    for (int e = 0; e < 8; ++e) {
        int k = kt * 32 + uu * 8 + e;
        dst[e] = f2bf(W[k * 256 + n]);
    }
}

__global__ __launch_bounds__(256, 2)
void fused_attn(const float* __restrict__ br0, const float* __restrict__ br1,
                const float* __restrict__ br2, const unsigned short* __restrict__ wt2,
                const float* __restrict__ bq, const float* __restrict__ bk,
                const float* __restrict__ bv, const float* __restrict__ bo,
                float* __restrict__ out) {
    // Xs: [0, 24576) bf16 X (never overwritten -> no X/O barrier).
    // Os: [32768, 57344) bf16 O [48][256]; Ys f32 [28][256] overlays [32768, 61440)
    // after all O reads complete. 61440B -> 2 blocks/CU (weight-L2-residency regime).
    __shared__ char ldsb[61440];
    char* Xs = ldsb;
    char* Os = ldsb + 32768;
    char* Ys = ldsb + 32768;

    const int t    = threadIdx.x;
    const int wave = t >> 6;            // = head index
    const int lane = t & 63;
    const int g    = lane & 15;
    const int u    = lane >> 4;
    const int b    = blockIdx.x >> 8;
    const int l0   = (blockIdx.x & 255) << 4;
    const int nb   = wave * 64;         // head column base
    const int cc   = lane * 4;

    const s16x8* WF = (const s16x8*)wt2;   // fragment-ordered weights

    // ---------------- phase 1: stage X (fused up-interp), bf16 swizzled ----------------
    {
        #pragma unroll
        for (int it = 0; it < 12; ++it) {
            int r = it * 4 + wave;      // wave-uniform row
            int n = r >> 4, p = r & 15;
            int l = l0 + p;
            float4 v;
            if (n == 0) {
                v = *(const float4*)(br0 + (size_t)(b * 4096 + l) * 256 + cc);
            } else {
                const float* src = (n == 1) ? br1 : br2;
                int   Lin   = (n == 1) ? 2048 : 1024;
                float scale = (n == 1) ? 0.5f : 0.25f;
                float sp = (l + 0.5f) * scale - 0.5f;
                sp = fminf(fmaxf(sp, 0.0f), (float)(Lin - 1));
                int i0 = (int)sp;
                int i1 = min(i0 + 1, Lin - 1);
                float w = sp - (float)i0;
                float4 a0 = *(const float4*)(src + (size_t)(b * Lin + i0) * 256 + cc);
                float4 a1 = *(const float4*)(src + (size_t)(b * Lin + i1) * 256 + cc);
                v.x = a0.x * (1.0f - w) + a1.x * w;
                v.y = a0.y * (1.0f - w) + a1.y * w;
                v.z = a0.z * (1.0f - w) + a1.z * w;
                v.w = a0.w * (1.0f - w) + a1.w * w;
            }
            u16x4 h;
            h.x = f2bf(v.x); h.y = f2bf(v.y); h.z = f2bf(v.z); h.w = f2bf(v.w);
            *(u16x4*)(Xs + swz(r, cc)) = h;
        }
    }
    __syncthreads();                                    // B1: X staged

    // --- phase 2: FUSED Q+K+V projection, KT-OUTER (12 weight loads in flight per kt) --
    float sc[3][3][4];                     // scores -> attention weights (in place)
    f32x4 vacc[3][4];                      // V accumulators (live through phase 4)
    {
        f32x4 qc[4][3], kc[4][3];
        #pragma unroll
        for (int tc = 0; tc < 4; ++tc)
            #pragma unroll
            for (int n = 0; n < 3; ++n) {
                qc[tc][n] = (f32x4){0.f, 0.f, 0.f, 0.f};
                kc[tc][n] = (f32x4){0.f, 0.f, 0.f, 0.f};
            }
        #pragma unroll
        for (int n = 0; n < 3; ++n)
            #pragma unroll
            for (int tc = 0; tc < 4; ++tc)
                vacc[n][tc] = (f32x4){0.f, 0.f, 0.f, 0.f};

        __builtin_amdgcn_s_setprio(1);
        #pragma unroll
        for (int kt = 0; kt < 8; ++kt) {
            s16x8 a[3];
            #pragma unroll
            for (int n = 0; n < 3; ++n)
                a[n] = *(const s16x8*)(Xs + swz(n * 16 + g, kt * 32 + u * 8));
            s16x8 bfq[4], bfk[4], bfv[4];
            #pragma unroll
            for (int tc = 0; tc < 4; ++tc) {
                const int ct = wave * 4 + tc;
                bfq[tc] = WF[((0 * 16 + ct) * 8 + kt) * 64 + lane];
                bfk[tc] = WF[((1 * 16 + ct) * 8 + kt) * 64 + lane];
                bfv[tc] = WF[((2 * 16 + ct) * 8 + kt) * 64 + lane];
            }
            #pragma unroll
            for (int tc = 0; tc < 4; ++tc)
                #pragma unroll
                for (int n = 0; n < 3; ++n) {
                    qc[tc][n]   = __builtin_amdgcn_mfma_f32_16x16x32_bf16(a[n], bfq[tc], qc[tc][n], 0, 0, 0);
                    kc[tc][n]   = __builtin_amdgcn_mfma_f32_16x16x32_bf16(a[n], bfk[tc], kc[tc][n], 0, 0, 0);
                    vacc[n][tc] = __builtin_amdgcn_mfma_f32_16x16x32_bf16(a[n], bfv[tc], vacc[n][tc], 0, 0, 0);
                }
        }
        __builtin_amdgcn_s_setprio(0);

        // scores: dot over the head's 64 dims = sum over tc (bias added per tc)
        #pragma unroll
        for (int n = 0; n < 3; ++n)
            #pragma unroll
            for (int m = 0; m < 3; ++m)
                #pragma unroll
                for (int j = 0; j < 4; ++j) sc[n][m][j] = 0.f;
        #pragma unroll
        for (int tc = 0; tc < 4; ++tc) {
            const float Bqv = bq[nb + tc * 16 + g];
            const float Bkv = bk[nb + tc * 16 + g];
            #pragma unroll
            for (int n = 0; n < 3; ++n)
                #pragma unroll
                for (int j = 0; j < 4; ++j) {
                    qc[tc][n][j] += Bqv;
                    kc[tc][n][j] += Bkv;
                }
            #pragma unroll
            for (int n = 0; n < 3; ++n)
                #pragma unroll
                for (int m = 0; m < 3; ++m)
                    #pragma unroll
                    for (int j = 0; j < 4; ++j)
                        sc[n][m][j] += qc[tc][n][j] * kc[tc][m][j];
        }
        // butterfly reduce over the 16 lanes (g) of each row group, via ds_swizzle
        #pragma unroll
        for (int n = 0; n < 3; ++n)
            #pragma unroll
            for (int m = 0; m < 3; ++m)
                #pragma unroll
                for (int j = 0; j < 4; ++j) {
                    SWZ_ADD(sc[n][m][j], 0x041F);   // xor 1
                    SWZ_ADD(sc[n][m][j], 0x081F);   // xor 2
                    SWZ_ADD(sc[n][m][j], 0x101F);   // xor 4
                    SWZ_ADD(sc[n][m][j], 0x201F);   // xor 8
                }
        // softmax over m (scale 1/sqrt(64)), in place
        #pragma unroll
        for (int n = 0; n < 3; ++n)
            #pragma unroll
            for (int j = 0; j < 4; ++j) {
                float s0 = sc[n][0][j] * 0.125f;
                float s1 = sc[n][1][j] * 0.125f;
                float s2 = sc[n][2][j] * 0.125f;
                float mx = fmaxf(s0, fmaxf(s1, s2));
                float e0 = __expf(s0 - mx), e1 = __expf(s1 - mx), e2 = __expf(s2 - mx);
                float inv = 1.0f / (e0 + e1 + e2);
                sc[n][0][j] = e0 * inv;
                sc[n][1][j] = e1 * inv;
                sc[n][2][j] = e2 * inv;
            }
    }
    // V bias
    #pragma unroll
    for (int tc = 0; tc < 4; ++tc) {
        const float Bvv = bv[nb + tc * 16 + g];
        #pragma unroll
        for (int n = 0; n < 3; ++n)
            #pragma unroll
            for (int j = 0; j < 4; ++j)
                vacc[n][tc][j] += Bvv;
    }

    // ---------------- phase 3: O = attn @ V (per-lane), write bf16 to Os ---------------
    #pragma unroll
    for (int n = 0; n < 3; ++n)
        #pragma unroll
        for (int tc = 0; tc < 4; ++tc)
            #pragma unroll
            for (int j = 0; j < 4; ++j) {
                float o = sc[n][0][j] * vacc[0][tc][j] +
                          sc[n][1][j] * vacc[1][tc][j] +
                          sc[n][2][j] * vacc[2][tc][j];
                *(unsigned short*)(Os + swz(n * 16 + u * 4 + j, nb + tc * 16 + g)) = f2bf(o);
            }
    __syncthreads();    // B2: O complete before cross-head reads

    // ---------------- phase 4: output projection (kt-outer, 4 loads in flight) ---------
    f32x4 yacc[3][4];
    #pragma unroll
    for (int n = 0; n < 3; ++n)
        #pragma unroll
        for (int tc = 0; tc < 4; ++tc)
            yacc[n][tc] = (f32x4){0.f, 0.f, 0.f, 0.f};
    __builtin_amdgcn_s_setprio(1);
    #pragma unroll
    for (int kt = 0; kt < 8; ++kt) {
        s16x8 a[3];
        #pragma unroll
        for (int n = 0; n < 3; ++n)
            a[n] = *(const s16x8*)(Os + swz(n * 16 + g, kt * 32 + u * 8));
        s16x8 bfo[4];
        #pragma unroll
        for (int tc = 0; tc < 4; ++tc)
            bfo[tc] = WF[((3 * 16 + wave * 4 + tc) * 8 + kt) * 64 + lane];
        #pragma unroll
        for (int tc = 0; tc < 4; ++tc)
            #pragma unroll
            for (int n = 0; n < 3; ++n)
                yacc[n][tc] = __builtin_amdgcn_mfma_f32_16x16x32_bf16(a[n], bfo[tc], yacc[n][tc], 0, 0, 0);
    }
    __builtin_amdgcn_s_setprio(0);
    __syncthreads();    // B3: all O reads done; Ys may overlay the Os region

    // ---------------- phase 5: stage Y (bias + down-interp) into LDS f32 ----------------
    // rows 0..15: branch0 ; 16..23: branch1 averaged ; 24..27: branch2 averaged
    #pragma unroll
    for (int tc = 0; tc < 4; ++tc) {
        int col = nb + tc * 16 + g;
        const float Bov = bo[col];
        #pragma unroll
        for (int j = 0; j < 4; ++j)
            *(float*)(Ys + swz32(u * 4 + j, col)) = yacc[0][tc][j] + Bov;
        #pragma unroll
        for (int jj = 0; jj < 2; ++jj)
            *(float*)(Ys + swz32(16 + u * 2 + jj, col)) =
                0.5f * (yacc[1][tc][2 * jj] + yacc[1][tc][2 * jj + 1]) + Bov;
        *(float*)(Ys + swz32(24 + u, col)) =
            0.5f * (yacc[2][tc][1] + yacc[2][tc][2]) + Bov;
    }
    __syncthreads();    // B4: Ys ready

    // ---------------- phase 6: coalesced f32x4 stores ----------------
    {
        // branch0: 16 rows
        #pragma unroll
        for (int it = 0; it < 4; ++it) {
            int r = it * 4 + wave;
            f32x4 v = *(const f32x4*)(Ys + swz32(r, cc));
            *(f32x4*)(out + (size_t)(b * 4096 + l0 + r) * 256 + cc) = v;
        }
        // branch1: 8 rows
        #pragma unroll
        for (int it = 0; it < 2; ++it) {
            int q = it * 4 + wave;
            f32x4 v = *(const f32x4*)(Ys + swz32(16 + q, cc));
            *(f32x4*)(out + 8388608 + (size_t)(b * 2048 + (l0 >> 1) + q) * 256 + cc) = v;
        }
        // branch2: 4 rows
        {
            f32x4 v = *(const f32x4*)(Ys + swz32(24 + wave, cc));
            *(f32x4*)(out + 12582912 + (size_t)(b * 1024 + (l0 >> 2) + wave) * 256 + cc) = v;
        }
    }
}

extern "C" void kernel_launch(void* const* d_in, const int* in_sizes, int n_in,
                              void* d_out, int out_size, void* d_ws, size_t ws_size,
                              hipStream_t stream) {
    const float* br0 = (const float*)d_in[0];
    const float* br1 = (const float*)d_in[1];
    const float* br2 = (const float*)d_in[2];
    const float* Wq  = (const float*)d_in[3];
    const float* bq  = (const float*)d_in[4];
    const float* Wk  = (const float*)d_in[5];
    const float* bk  = (const float*)d_in[6];
    const float* Wv  = (const float*)d_in[7];
    const float* bv  = (const float*)d_in[8];
    const float* Wo  = (const float*)d_in[9];
    const float* bo  = (const float*)d_in[10];

    unsigned short* wt2 = (unsigned short*)d_ws;  // 4*256*256 bf16 = 512 KB, fragment order

    prep_w<<<128, 256, 0, stream>>>(Wq, Wk, Wv, Wo, wt2);
    fused_attn<<<2048, 256, 0, stream>>>(br0, br1, br2, wt2, bq, bk, bv, bo,
                                         (float*)d_out);
}